// Round 1
// baseline (98.373 us; speedup 1.0000x reference)
//
#include <hip/hip_runtime.h>
#include <math.h>

// NetVLAD fused pipeline, fp32 baseline.
// Shapes: x[32][128][4096], conv_w[64][128], conv_b[64], centers[64][128],
//         mlp_w[256][8192], mlp_b[256], out[32][256].

#define N_IMG 32
#define C_DIM 128
#define P_PIX 4096
#define K_CL  64
#define OUT_D 256

#define CHUNKS 16          // chunks per image (kernel A)
#define PX_CHUNK 256       // pixels per chunk
#define PJ 32              // pixels per subtile
#define NSUB 8             // subtiles per chunk
#define PART_ROW 132       // per-k row stride in partials (128 c + asum + pad)
#define PART_BLK (K_CL * PART_ROW)   // 8448 floats per A-block

// ---------------------------------------------------------------------------
// Kernel A: fused 1x1-conv logits + softmax + VLAD accumulation (partials).
// grid = 512 (n = bid>>4, chunk = bid&15), block = 256.
// LDS ~79KB -> 2 blocks/CU (8 waves/CU).
// ---------------------------------------------------------------------------
__global__ __launch_bounds__(256, 2)
void k_vlad(const float* __restrict__ x, const float* __restrict__ conv_w,
            const float* __restrict__ conv_b, float* __restrict__ part)
{
    __shared__ float w_s[C_DIM][68];   // w_s[c][k]  (stride 68: bank-safe b128)
    __shared__ float xc_s[C_DIM][36];  // x[c][j]    (logits reads, b64 over j)
    __shared__ float xj_s[PJ][132];    // x[j][c]    (vlad reads, b128 over c)
    __shared__ float e_s[PJ][68];      // logits -> softmax a[j][k]
    __shared__ float b_s[K_CL];

    const int t  = threadIdx.x;
    const int n  = blockIdx.x >> 4;
    const int ch = blockIdx.x & 15;

    // stage conv_w transposed (w_s[c][k]) + bias
    for (int idx = t; idx < K_CL * C_DIM; idx += 256) {
        const int k = idx >> 7, c = idx & 127;
        w_s[c][k] = conv_w[idx];
    }
    if (t < K_CL) b_s[t] = conv_b[t];

    const int kq = t & 15;   // k-quad id (k0 = kq*4), used by logits & vlad
    const int hi = t >> 4;   // logits: j-pair id; vlad: c-group id (c0 = hi*8)

    // persistent accumulators: vlad tile 4k x 8c per thread + asum (hi==0)
    float vacc[4][8];
#pragma unroll
    for (int a = 0; a < 4; ++a)
#pragma unroll
        for (int b = 0; b < 8; ++b) vacc[a][b] = 0.f;
    float asum[4] = {0.f, 0.f, 0.f, 0.f};

    // staging assignment: thread -> (row c, half of 32 pixels)
    const int cld = t >> 1;
    const int jh  = t & 1;
    const float* xrow = x + ((long)n * C_DIM + cld) * P_PIX + ch * PX_CHUNK + jh * 16;

    // prologue load (software pipeline: next subtile loaded during compute)
    float4 v0 = *(const float4*)(xrow + 0);
    float4 v1 = *(const float4*)(xrow + 4);
    float4 v2 = *(const float4*)(xrow + 8);
    float4 v3 = *(const float4*)(xrow + 12);

    for (int sub = 0; sub < NSUB; ++sub) {
        __syncthreads();  // previous subtile's vlad reads done
        // ---- stage x into both layouts ----
        *(float4*)&xc_s[cld][jh * 16 + 0]  = v0;
        *(float4*)&xc_s[cld][jh * 16 + 4]  = v1;
        *(float4*)&xc_s[cld][jh * 16 + 8]  = v2;
        *(float4*)&xc_s[cld][jh * 16 + 12] = v3;
        {
            const int jb = jh * 16;
            xj_s[jb + 0][cld] = v0.x;  xj_s[jb + 1][cld] = v0.y;
            xj_s[jb + 2][cld] = v0.z;  xj_s[jb + 3][cld] = v0.w;
            xj_s[jb + 4][cld] = v1.x;  xj_s[jb + 5][cld] = v1.y;
            xj_s[jb + 6][cld] = v1.z;  xj_s[jb + 7][cld] = v1.w;
            xj_s[jb + 8][cld] = v2.x;  xj_s[jb + 9][cld] = v2.y;
            xj_s[jb + 10][cld] = v2.z; xj_s[jb + 11][cld] = v2.w;
            xj_s[jb + 12][cld] = v3.x; xj_s[jb + 13][cld] = v3.y;
            xj_s[jb + 14][cld] = v3.z; xj_s[jb + 15][cld] = v3.w;
        }
        // prefetch next subtile while we compute this one
        if (sub + 1 < NSUB) {
            const float* nx = xrow + (sub + 1) * PJ;
            v0 = *(const float4*)(nx + 0);
            v1 = *(const float4*)(nx + 4);
            v2 = *(const float4*)(nx + 8);
            v3 = *(const float4*)(nx + 12);
        }
        __syncthreads();

        // ---- logits: thread computes 4k x 2j, write raw logits to e_s ----
        {
            const int k0 = kq * 4, j0 = hi * 2;
            float a00 = 0.f, a01 = 0.f, a10 = 0.f, a11 = 0.f;
            float a20 = 0.f, a21 = 0.f, a30 = 0.f, a31 = 0.f;
#pragma unroll 4
            for (int c = 0; c < C_DIM; ++c) {
                const float4 w4 = *(const float4*)&w_s[c][k0];
                const float xa = xc_s[c][j0];
                const float xb = xc_s[c][j0 + 1];
                a00 = fmaf(w4.x, xa, a00); a01 = fmaf(w4.x, xb, a01);
                a10 = fmaf(w4.y, xa, a10); a11 = fmaf(w4.y, xb, a11);
                a20 = fmaf(w4.z, xa, a20); a21 = fmaf(w4.z, xb, a21);
                a30 = fmaf(w4.w, xa, a30); a31 = fmaf(w4.w, xb, a31);
            }
            const float4 bb = *(const float4*)&b_s[k0];
            *(float4*)&e_s[j0][k0] =
                make_float4(a00 + bb.x, a10 + bb.y, a20 + bb.z, a30 + bb.w);
            *(float4*)&e_s[j0 + 1][k0] =
                make_float4(a01 + bb.x, a11 + bb.y, a21 + bb.z, a31 + bb.w);
        }
        __syncthreads();

        // ---- softmax over k (64) per pixel: 8 lanes per pixel ----
        {
            const int j = t >> 3, o = t & 7;
            float4 va = *(const float4*)&e_s[j][o * 8];
            float4 vb = *(const float4*)&e_s[j][o * 8 + 4];
            float m = fmaxf(fmaxf(fmaxf(va.x, va.y), fmaxf(va.z, va.w)),
                            fmaxf(fmaxf(vb.x, vb.y), fmaxf(vb.z, vb.w)));
            m = fmaxf(m, __shfl_xor(m, 1));
            m = fmaxf(m, __shfl_xor(m, 2));
            m = fmaxf(m, __shfl_xor(m, 4));
            va.x = __expf(va.x - m); va.y = __expf(va.y - m);
            va.z = __expf(va.z - m); va.w = __expf(va.w - m);
            vb.x = __expf(vb.x - m); vb.y = __expf(vb.y - m);
            vb.z = __expf(vb.z - m); vb.w = __expf(vb.w - m);
            float s = va.x + va.y + va.z + va.w + vb.x + vb.y + vb.z + vb.w;
            s += __shfl_xor(s, 1);
            s += __shfl_xor(s, 2);
            s += __shfl_xor(s, 4);
            const float rinv = 1.0f / s;
            va.x *= rinv; va.y *= rinv; va.z *= rinv; va.w *= rinv;
            vb.x *= rinv; vb.y *= rinv; vb.z *= rinv; vb.w *= rinv;
            *(float4*)&e_s[j][o * 8]     = va;
            *(float4*)&e_s[j][o * 8 + 4] = vb;
        }
        __syncthreads();

        // ---- vlad accumulate: thread tile 4k x 8c, loop over 32 pixels ----
        {
            const int k0 = kq * 4, c0 = hi * 8;
#pragma unroll 2
            for (int j = 0; j < PJ; ++j) {
                const float4 a4 = *(const float4*)&e_s[j][k0];
                if (hi == 0) {  // only wave-0 lanes: fold asum in (free slot)
                    asum[0] += a4.x; asum[1] += a4.y;
                    asum[2] += a4.z; asum[3] += a4.w;
                }
                const float4 x0 = *(const float4*)&xj_s[j][c0];
                const float4 x1 = *(const float4*)&xj_s[j][c0 + 4];
                vacc[0][0] = fmaf(a4.x, x0.x, vacc[0][0]);
                vacc[0][1] = fmaf(a4.x, x0.y, vacc[0][1]);
                vacc[0][2] = fmaf(a4.x, x0.z, vacc[0][2]);
                vacc[0][3] = fmaf(a4.x, x0.w, vacc[0][3]);
                vacc[0][4] = fmaf(a4.x, x1.x, vacc[0][4]);
                vacc[0][5] = fmaf(a4.x, x1.y, vacc[0][5]);
                vacc[0][6] = fmaf(a4.x, x1.z, vacc[0][6]);
                vacc[0][7] = fmaf(a4.x, x1.w, vacc[0][7]);
                vacc[1][0] = fmaf(a4.y, x0.x, vacc[1][0]);
                vacc[1][1] = fmaf(a4.y, x0.y, vacc[1][1]);
                vacc[1][2] = fmaf(a4.y, x0.z, vacc[1][2]);
                vacc[1][3] = fmaf(a4.y, x0.w, vacc[1][3]);
                vacc[1][4] = fmaf(a4.y, x1.x, vacc[1][4]);
                vacc[1][5] = fmaf(a4.y, x1.y, vacc[1][5]);
                vacc[1][6] = fmaf(a4.y, x1.z, vacc[1][6]);
                vacc[1][7] = fmaf(a4.y, x1.w, vacc[1][7]);
                vacc[2][0] = fmaf(a4.z, x0.x, vacc[2][0]);
                vacc[2][1] = fmaf(a4.z, x0.y, vacc[2][1]);
                vacc[2][2] = fmaf(a4.z, x0.z, vacc[2][2]);
                vacc[2][3] = fmaf(a4.z, x0.w, vacc[2][3]);
                vacc[2][4] = fmaf(a4.z, x1.x, vacc[2][4]);
                vacc[2][5] = fmaf(a4.z, x1.y, vacc[2][5]);
                vacc[2][6] = fmaf(a4.z, x1.z, vacc[2][6]);
                vacc[2][7] = fmaf(a4.z, x1.w, vacc[2][7]);
                vacc[3][0] = fmaf(a4.w, x0.x, vacc[3][0]);
                vacc[3][1] = fmaf(a4.w, x0.y, vacc[3][1]);
                vacc[3][2] = fmaf(a4.w, x0.z, vacc[3][2]);
                vacc[3][3] = fmaf(a4.w, x0.w, vacc[3][3]);
                vacc[3][4] = fmaf(a4.w, x1.x, vacc[3][4]);
                vacc[3][5] = fmaf(a4.w, x1.y, vacc[3][5]);
                vacc[3][6] = fmaf(a4.w, x1.z, vacc[3][6]);
                vacc[3][7] = fmaf(a4.w, x1.w, vacc[3][7]);
            }
        }
    }

    // ---- write partials: part[bid][k][c], asum at c=128 ----
    const long pbase = (long)blockIdx.x * PART_BLK;
    const int k0 = kq * 4, c0 = hi * 8;
#pragma unroll
    for (int ki = 0; ki < 4; ++ki) {
        *(float4*)&part[pbase + (k0 + ki) * PART_ROW + c0] =
            make_float4(vacc[ki][0], vacc[ki][1], vacc[ki][2], vacc[ki][3]);
        *(float4*)&part[pbase + (k0 + ki) * PART_ROW + c0 + 4] =
            make_float4(vacc[ki][4], vacc[ki][5], vacc[ki][6], vacc[ki][7]);
    }
    if (hi == 0) {
#pragma unroll
        for (int ki = 0; ki < 4; ++ki)
            part[pbase + (k0 + ki) * PART_ROW + 128] = asum[ki];
    }
}

// ---------------------------------------------------------------------------
// Kernel B: reduce partials, subtract asum*centers, intra-normalize per (n,k).
// grid = 2048 (n = b>>6, k = b&63), block = 128 (c = tid).
// ---------------------------------------------------------------------------
__global__ __launch_bounds__(128)
void k_reduce_norm(const float* __restrict__ part, const float* __restrict__ centers,
                   float* __restrict__ vnorm, float* __restrict__ rsq)
{
    const int b = blockIdx.x;
    const int n = b >> 6, k = b & 63;
    const int c = threadIdx.x;
    float acc = 0.f, as = 0.f;
#pragma unroll 4
    for (int ch = 0; ch < CHUNKS; ++ch) {
        const float* p = part + ((long)(n * CHUNKS + ch) * PART_BLK + k * PART_ROW);
        acc += p[c];
        as  += p[128];
    }
    const float v = fmaf(-as, centers[k * C_DIM + c], acc);
    float sq = v * v;
#pragma unroll
    for (int m = 1; m < 64; m <<= 1) sq += __shfl_xor(sq, m);
    __shared__ float red[2];
    if ((c & 63) == 0) red[c >> 6] = sq;
    __syncthreads();
    const float total = red[0] + red[1];
    const float s = 1.0f / fmaxf(sqrtf(total), 1e-12f);
    vnorm[(long)n * 8192 + k * C_DIM + c] = v * s;
    if (c == 0) rsq[n * K_CL + k] = total * s * s;  // post-norm row sumsq
}

// ---------------------------------------------------------------------------
// Kernel C: MLP partial GEMM. Block = (og = bid&7 : 32 out cols, jc = bid>>3 :
// 256-wide j slice). All 32 images in-block -> mlp_w read exactly once.
// ---------------------------------------------------------------------------
__global__ __launch_bounds__(256)
void k_mlp(const float* __restrict__ vnorm, const float* __restrict__ mlp_w,
           float* __restrict__ part2)
{
    __shared__ float vn_s[32][260];
    __shared__ float w_ss[32][260];
    const int t = threadIdx.x;
    const int og = blockIdx.x & 7;
    const int jc = blockIdx.x >> 3;
    const int jb = jc * 256;
#pragma unroll
    for (int r = 0; r < 8; ++r) {
        const int flat = r * 256 + t;
        const int row = flat >> 6, pos = (flat & 63) * 4;
        *(float4*)&vn_s[row][pos] = *(const float4*)&vnorm[(long)row * 8192 + jb + pos];
    }
#pragma unroll
    for (int r = 0; r < 8; ++r) {
        const int flat = r * 256 + t;
        const int row = flat >> 6, pos = (flat & 63) * 4;
        *(float4*)&w_ss[row][pos] =
            *(const float4*)&mlp_w[(long)(og * 32 + row) * 8192 + jb + pos];
    }
    __syncthreads();
    const int oo = t & 15, nn = t >> 4;
    float a00 = 0.f, a01 = 0.f, a10 = 0.f, a11 = 0.f;
#pragma unroll 4
    for (int jj = 0; jj < 64; ++jj) {
        const float4 wa = *(const float4*)&w_ss[oo][jj * 4];
        const float4 wb = *(const float4*)&w_ss[oo + 16][jj * 4];
        const float4 va = *(const float4*)&vn_s[nn][jj * 4];
        const float4 vb = *(const float4*)&vn_s[nn + 16][jj * 4];
        a00 = fmaf(wa.x, va.x, fmaf(wa.y, va.y, fmaf(wa.z, va.z, fmaf(wa.w, va.w, a00))));
        a01 = fmaf(wa.x, vb.x, fmaf(wa.y, vb.y, fmaf(wa.z, vb.z, fmaf(wa.w, vb.w, a01))));
        a10 = fmaf(wb.x, va.x, fmaf(wb.y, va.y, fmaf(wb.z, va.z, fmaf(wb.w, va.w, a10))));
        a11 = fmaf(wb.x, vb.x, fmaf(wb.y, vb.y, fmaf(wb.z, vb.z, fmaf(wb.w, vb.w, a11))));
    }
    const int ob = og * 32;
    part2[(jc * 32 + nn)      * 256 + ob + oo]      = a00;
    part2[(jc * 32 + nn + 16) * 256 + ob + oo]      = a01;
    part2[(jc * 32 + nn)      * 256 + ob + oo + 16] = a10;
    part2[(jc * 32 + nn + 16) * 256 + ob + oo + 16] = a11;
}

// ---------------------------------------------------------------------------
// Kernel D: reduce j-slices, global-norm scale, bias, final L2 norm.
// grid = 32 (n), block = 256 (o).
// ---------------------------------------------------------------------------
__global__ __launch_bounds__(256)
void k_finalize(const float* __restrict__ part2, const float* __restrict__ mlp_b,
                const float* __restrict__ rsq, float* __restrict__ out)
{
    const int n = blockIdx.x, o = threadIdx.x;
    float g = 0.f;
#pragma unroll
    for (int i = 0; i < 16; ++i) {
        const float4 r = *(const float4*)&rsq[n * K_CL + i * 4];
        g += r.x + r.y + r.z + r.w;
    }
    const float s = 1.0f / fmaxf(sqrtf(g), 1e-12f);
    float acc = 0.f;
#pragma unroll
    for (int jc = 0; jc < 32; ++jc) acc += part2[(jc * 32 + n) * 256 + o];
    const float y = fmaf(acc, s, mlp_b[o]);
    float sq = y * y;
#pragma unroll
    for (int m = 1; m < 64; m <<= 1) sq += __shfl_xor(sq, m);
    __shared__ float red[4];
    if ((o & 63) == 0) red[o >> 6] = sq;
    __syncthreads();
    const float tot = red[0] + red[1] + red[2] + red[3];
    out[n * OUT_D + o] = y / fmaxf(sqrtf(tot), 1e-12f);
}

// ---------------------------------------------------------------------------
extern "C" void kernel_launch(void* const* d_in, const int* in_sizes, int n_in,
                              void* d_out, int out_size, void* d_ws, size_t ws_size,
                              hipStream_t stream)
{
    const float* x       = (const float*)d_in[0];
    const float* centers = (const float*)d_in[1];
    const float* conv_w  = (const float*)d_in[2];
    const float* conv_b  = (const float*)d_in[3];
    const float* mlp_w   = (const float*)d_in[4];
    const float* mlp_b   = (const float*)d_in[5];

    float* ws    = (float*)d_ws;
    float* part  = ws;                         // 512*8448      = 4,325,376 f
    float* vnorm = part + 512 * PART_BLK;      // 32*8192       =   262,144 f
    float* rsq   = vnorm + 32 * 8192;          // 32*64         =     2,048 f
    float* part2 = rsq + 2048;                 // 32jc*32n*256o =   262,144 f
                                               // total ~18.5 MB

    k_vlad<<<dim3(512), dim3(256), 0, stream>>>(x, conv_w, conv_b, part);
    k_reduce_norm<<<dim3(2048), dim3(128), 0, stream>>>(part, centers, vnorm, rsq);
    k_mlp<<<dim3(256), dim3(256), 0, stream>>>(vnorm, mlp_w, part2);
    k_finalize<<<dim3(32), dim3(256), 0, stream>>>(part2, mlp_b, rsq, (float*)d_out);
}

// Round 2
// 52.227 us; speedup vs baseline: 1.8836x; 1.8836x over previous
//
#include <hip/hip_runtime.h>
#include <math.h>

// NetVLAD fused pipeline. Kernel A rewritten on MFMA bf16 16x16x32.
// Shapes: x[32][128][4096], conv_w[64][128], conv_b[64], centers[64][128],
//         mlp_w[256][8192], mlp_b[256], out[32][256].

#define N_IMG 32
#define C_DIM 128
#define P_PIX 4096
#define K_CL  64
#define OUT_D 256

#define CHUNKS 16
#define PART_ROW 132
#define PART_BLK (K_CL * PART_ROW)

typedef __attribute__((ext_vector_type(8))) short bf16x8;
typedef __attribute__((ext_vector_type(4))) short bf16x4;
typedef __attribute__((ext_vector_type(4))) float f32x4;
typedef __attribute__((ext_vector_type(2))) unsigned u32x2;
typedef __attribute__((ext_vector_type(4))) unsigned u32x4;

// pack two fp32 -> bf16 pair (RTNE), low = a, high = b
__device__ __forceinline__ unsigned bfpk(float a, float b) {
    union { float f; unsigned u; } x, y;
    x.f = a; y.f = b;
    unsigned lo = (x.u + 0x7FFFu + ((x.u >> 16) & 1u)) >> 16;
    unsigned hi = (y.u + 0x7FFFu + ((y.u >> 16) & 1u)) & 0xFFFF0000u;
    return lo | hi;
}

__device__ __forceinline__ f32x4 mfma16(bf16x8 a, bf16x8 b, f32x4 c) {
    return __builtin_amdgcn_mfma_f32_16x16x32_bf16(a, b, c, 0, 0, 0);
}

// hardware transpose read: 4 bf16 at addr + {0,32,64,96} bytes
__device__ __forceinline__ u32x2 tr16(unsigned addr) {
    u32x2 d;
    asm volatile("ds_read_b64_tr_b16 %0, %1" : "=v"(d) : "v"(addr));
    return d;
}
__device__ __forceinline__ u32x2 tr16_o1024(unsigned addr) {
    u32x2 d;
    asm volatile("ds_read_b64_tr_b16 %0, %1 offset:1024" : "=v"(d) : "v"(addr));
    return d;
}

// ---------------------------------------------------------------------------
// Kernel A (MFMA): fused 1x1-conv logits + softmax + VLAD partial accumulation.
// grid = 512 (n = bid>>4, 256-pixel chunk = bid&15), block = 256 (4 waves).
// Per 128p subchunk: GEMM1 logits^T[p][k] = x^T[p][c] @ W^T[c][k] (A via
// tr_b16 from subtiled LDS, B = W from regs); softmax in-register over k;
// GEMM2 vlad[k][c] += a[k][p] @ x^T[p][c] (A from swizzled a_lds, B = the
// x octets still in registers). LDS ~49 KB -> 2 blocks/CU.
// ---------------------------------------------------------------------------
__global__ __launch_bounds__(256, 2)
void k_vlad_mfma(const float* __restrict__ x, const float* __restrict__ conv_w,
                 const float* __restrict__ conv_b, float* __restrict__ part)
{
    __shared__ short xc_s[16384];   // x subtiled [c>>2][p>>4][c&3][p&15], 32 KB
    __shared__ short a_s[8192];     // a[k][p] bf16, byte ^ ((k&7)<<4), 16 KB
    __shared__ float asred[4 * 64]; // per-wave asum partials

    const int t   = threadIdx.x;
    const int w   = t >> 6;
    const int l   = t & 63;
    const int l15 = l & 15;
    const int lg  = l >> 4;
    const int n   = blockIdx.x >> 4;
    const int ch  = blockIdx.x & 15;
    const int pb0 = ch * 256;

    const unsigned xc_base = (unsigned)(unsigned long long)(void*)xc_s;

    // ---- issue x(subchunk 0) global loads first (hide under W-load) ----
    const float* xr0 = x + ((long)n * C_DIM + 32 * w + l15) * P_PIX;
    const float* xr1 = xr0 + 16 * P_PIX;
    float4 raw[16];
#pragma unroll
    for (int h = 0; h < 2; ++h) {
        const float* xr = h ? xr1 : xr0;
#pragma unroll
        for (int ks = 0; ks < 4; ++ks) {
            const float* p = xr + pb0 + ks * 32 + lg * 8;
            raw[(h * 4 + ks) * 2 + 0] = *(const float4*)(p);
            raw[(h * 4 + ks) * 2 + 1] = *(const float4*)(p + 4);
        }
    }

    // ---- W fragments (GEMM1 B-operand): lane k-col = nt*16+l15,
    //      kdim c = ks*32 + lg*8 + j ----
    bf16x8 wf[4][4];
#pragma unroll
    for (int nt = 0; nt < 4; ++nt) {
        const float* wr = conv_w + (nt * 16 + l15) * C_DIM;
#pragma unroll
        for (int ks = 0; ks < 4; ++ks) {
            float4 a = *(const float4*)(wr + ks * 32 + lg * 8);
            float4 b = *(const float4*)(wr + ks * 32 + lg * 8 + 4);
            union { u32x4 u; bf16x8 v; } cv;
            cv.u.x = bfpk(a.x, a.y); cv.u.y = bfpk(a.z, a.w);
            cv.u.z = bfpk(b.x, b.y); cv.u.w = bfpk(b.z, b.w);
            wf[nt][ks] = cv.v;
        }
    }
    float bias[4];
#pragma unroll
    for (int nt = 0; nt < 4; ++nt) bias[nt] = conv_b[nt * 16 + l15];

    f32x4 acc2[4][2];               // vlad acc: [mt over k][h over c]
#pragma unroll
    for (int mt = 0; mt < 4; ++mt)
#pragma unroll
        for (int h = 0; h < 2; ++h)
            acc2[mt][h] = (f32x4){0.f, 0.f, 0.f, 0.f};
    float asum[4] = {0.f, 0.f, 0.f, 0.f};
    bf16x8 oct[2][4];               // x bf16 octets: GEMM2 B-frags

#pragma unroll
    for (int s = 0; s < 2; ++s) {
        // ---- convert raw -> bf16 octets ----
#pragma unroll
        for (int h = 0; h < 2; ++h)
#pragma unroll
            for (int ks = 0; ks < 4; ++ks) {
                const float4 A = raw[(h * 4 + ks) * 2];
                const float4 B = raw[(h * 4 + ks) * 2 + 1];
                union { u32x4 u; bf16x8 v; } cv;
                cv.u.x = bfpk(A.x, A.y); cv.u.y = bfpk(A.z, A.w);
                cv.u.z = bfpk(B.x, B.y); cv.u.w = bfpk(B.z, B.w);
                oct[h][ks] = cv.v;
            }
        // ---- stage into subtiled xc (b128, bank-balanced) ----
#pragma unroll
        for (int h = 0; h < 2; ++h)
#pragma unroll
            for (int ks = 0; ks < 4; ++ks) {
                const int c  = 32 * w + 16 * h + l15;
                const int pl = ks * 32 + lg * 8;
                const unsigned off = (unsigned)((c >> 2) * 1024 + (pl >> 4) * 128
                                                + (c & 3) * 32 + (pl & 15) * 2);
                *(bf16x8*)((char*)xc_s + off) = oct[h][ks];
            }
        __syncthreads();   // B1: xc staged; a_s free (prev GEMM2 done)

        // ---- GEMM1: logits^T[p][k], acc1[pt'][nt] ----
        f32x4 acc1[2][4];
#pragma unroll
        for (int pt2 = 0; pt2 < 2; ++pt2)
#pragma unroll
            for (int nt = 0; nt < 4; ++nt)
                acc1[pt2][nt] = (f32x4){0.f, 0.f, 0.f, 0.f};
#pragma unroll
        for (int ks = 0; ks < 4; ++ks) {
            // A-frag (x^T): p-row = (2w+pt')*16 + l15, c = ks*32 + lg*8 + j
            const unsigned ab = xc_base
                + (unsigned)((ks * 8 + lg * 2) * 1024 + l15 * 2);
            u32x2 t00 = tr16(ab + (2 * w + 0) * 128);
            u32x2 t01 = tr16_o1024(ab + (2 * w + 0) * 128);
            u32x2 t10 = tr16(ab + (2 * w + 1) * 128);
            u32x2 t11 = tr16_o1024(ab + (2 * w + 1) * 128);
            asm volatile("s_waitcnt lgkmcnt(0)" ::: "memory");
            __builtin_amdgcn_sched_barrier(0);
            union { u32x4 u; bf16x8 v; } a0, a1;
            a0.u = (u32x4){t00.x, t00.y, t01.x, t01.y};
            a1.u = (u32x4){t10.x, t10.y, t11.x, t11.y};
#pragma unroll
            for (int nt = 0; nt < 4; ++nt) {
                acc1[0][nt] = mfma16(a0.v, wf[nt][ks], acc1[0][nt]);
                acc1[1][nt] = mfma16(a1.v, wf[nt][ks], acc1[1][nt]);
            }
        }

        // ---- softmax over k (in-register; 16-lane shfl groups share p-row) ----
#pragma unroll
        for (int pt2 = 0; pt2 < 2; ++pt2) {
#pragma unroll
            for (int r = 0; r < 4; ++r) {
                float v0 = acc1[pt2][0][r] + bias[0];
                float v1 = acc1[pt2][1][r] + bias[1];
                float v2 = acc1[pt2][2][r] + bias[2];
                float v3 = acc1[pt2][3][r] + bias[3];
                float m = fmaxf(fmaxf(v0, v1), fmaxf(v2, v3));
                m = fmaxf(m, __shfl_xor(m, 1));
                m = fmaxf(m, __shfl_xor(m, 2));
                m = fmaxf(m, __shfl_xor(m, 4));
                m = fmaxf(m, __shfl_xor(m, 8));
                v0 = __expf(v0 - m); v1 = __expf(v1 - m);
                v2 = __expf(v2 - m); v3 = __expf(v3 - m);
                float sm = v0 + v1 + v2 + v3;
                sm += __shfl_xor(sm, 1);
                sm += __shfl_xor(sm, 2);
                sm += __shfl_xor(sm, 4);
                sm += __shfl_xor(sm, 8);
                const float inv = __fdividef(1.0f, sm);
                v0 *= inv; v1 *= inv; v2 *= inv; v3 *= inv;
                asum[0] += v0; asum[1] += v1; asum[2] += v2; asum[3] += v3;
                acc1[pt2][0][r] = v0; acc1[pt2][1][r] = v1;
                acc1[pt2][2][r] = v2; acc1[pt2][3][r] = v3;
            }
        }
        // ---- write a -> a_lds[k][p] (b64 of 4 consecutive p, swizzled) ----
#pragma unroll
        for (int pt2 = 0; pt2 < 2; ++pt2) {
            const int pbyte = (2 * w + pt2) * 32 + lg * 8;
#pragma unroll
            for (int nt = 0; nt < 4; ++nt) {
                const int k = nt * 16 + l15;
                union { u32x2 u; bf16x4 v; } pk4;
                pk4.u.x = bfpk(acc1[pt2][nt][0], acc1[pt2][nt][1]);
                pk4.u.y = bfpk(acc1[pt2][nt][2], acc1[pt2][nt][3]);
                const unsigned off =
                    (unsigned)(k * 256 + (pbyte ^ ((k & 7) << 4)));
                *(bf16x4*)((char*)a_s + off) = pk4.v;
            }
        }
        // ---- prefetch next subchunk's x (in flight across GEMM2) ----
        if (s == 0) {
#pragma unroll
            for (int h = 0; h < 2; ++h) {
                const float* xr = h ? xr1 : xr0;
#pragma unroll
                for (int ks = 0; ks < 4; ++ks) {
                    const float* p = xr + pb0 + 128 + ks * 32 + lg * 8;
                    raw[(h * 4 + ks) * 2 + 0] = *(const float4*)(p);
                    raw[(h * 4 + ks) * 2 + 1] = *(const float4*)(p + 4);
                }
            }
        }
        __syncthreads();   // B2: a ready; xc free

        // ---- GEMM2: vlad[k][c] += a[k][p] @ x^T[p][c] ----
#pragma unroll
        for (int ks = 0; ks < 4; ++ks) {
            bf16x8 af[4];
#pragma unroll
            for (int mt = 0; mt < 4; ++mt) {
                const int k = mt * 16 + l15;
                const unsigned off = (unsigned)(k * 256
                    + ((ks * 64 + lg * 16) ^ ((k & 7) << 4)));
                af[mt] = *(const bf16x8*)((char*)a_s + off);
            }
#pragma unroll
            for (int mt = 0; mt < 4; ++mt)
#pragma unroll
                for (int h = 0; h < 2; ++h)
                    acc2[mt][h] = mfma16(af[mt], oct[h][ks], acc2[mt][h]);
        }
    }

    // ---- write partials: part[bid][k][c], asum at c=128 ----
    const long pbase = (long)blockIdx.x * PART_BLK;
#pragma unroll
    for (int mt = 0; mt < 4; ++mt)
#pragma unroll
        for (int h = 0; h < 2; ++h) {
            const int c = 32 * w + 16 * h + l15;
#pragma unroll
            for (int r = 0; r < 4; ++r) {
                const int k = mt * 16 + lg * 4 + r;
                part[pbase + (long)k * PART_ROW + c] = acc2[mt][h][r];
            }
        }
#pragma unroll
    for (int nt = 0; nt < 4; ++nt) {
        float a = asum[nt];
        a += __shfl_xor(a, 16);
        a += __shfl_xor(a, 32);
        if (lg == 0) asred[w * 64 + nt * 16 + l15] = a;
    }
    __syncthreads();
    if (t < 64) {
        float a = asred[t] + asred[64 + t] + asred[128 + t] + asred[192 + t];
        part[pbase + (long)t * PART_ROW + 128] = a;
    }
}

// ---------------------------------------------------------------------------
// Kernel B: reduce partials, subtract asum*centers, intra-normalize per (n,k).
// ---------------------------------------------------------------------------
__global__ __launch_bounds__(128)
void k_reduce_norm(const float* __restrict__ part, const float* __restrict__ centers,
                   float* __restrict__ vnorm, float* __restrict__ rsq)
{
    const int b = blockIdx.x;
    const int n = b >> 6, k = b & 63;
    const int c = threadIdx.x;
    float acc = 0.f, as = 0.f;
#pragma unroll 4
    for (int ch = 0; ch < CHUNKS; ++ch) {
        const float* p = part + ((long)(n * CHUNKS + ch) * PART_BLK + k * PART_ROW);
        acc += p[c];
        as  += p[128];
    }
    const float v = fmaf(-as, centers[k * C_DIM + c], acc);
    float sq = v * v;
#pragma unroll
    for (int m = 1; m < 64; m <<= 1) sq += __shfl_xor(sq, m);
    __shared__ float red[2];
    if ((c & 63) == 0) red[c >> 6] = sq;
    __syncthreads();
    const float total = red[0] + red[1];
    const float s = 1.0f / fmaxf(sqrtf(total), 1e-12f);
    vnorm[(long)n * 8192 + k * C_DIM + c] = v * s;
    if (c == 0) rsq[n * K_CL + k] = total * s * s;
}

// ---------------------------------------------------------------------------
// Kernel C: MLP partial GEMM (mlp_w read exactly once).
// ---------------------------------------------------------------------------
__global__ __launch_bounds__(256)
void k_mlp(const float* __restrict__ vnorm, const float* __restrict__ mlp_w,
           float* __restrict__ part2)
{
    __shared__ float vn_s[32][260];
    __shared__ float w_ss[32][260];
    const int t = threadIdx.x;
    const int og = blockIdx.x & 7;
    const int jc = blockIdx.x >> 3;
    const int jb = jc * 256;
#pragma unroll
    for (int r = 0; r < 8; ++r) {
        const int flat = r * 256 + t;
        const int row = flat >> 6, pos = (flat & 63) * 4;
        *(float4*)&vn_s[row][pos] = *(const float4*)&vnorm[(long)row * 8192 + jb + pos];
    }
#pragma unroll
    for (int r = 0; r < 8; ++r) {
        const int flat = r * 256 + t;
        const int row = flat >> 6, pos = (flat & 63) * 4;
        *(float4*)&w_ss[row][pos] =
            *(const float4*)&mlp_w[(long)(og * 32 + row) * 8192 + jb + pos];
    }
    __syncthreads();
    const int oo = t & 15, nn = t >> 4;
    float a00 = 0.f, a01 = 0.f, a10 = 0.f, a11 = 0.f;
#pragma unroll 4
    for (int jj = 0; jj < 64; ++jj) {
        const float4 wa = *(const float4*)&w_ss[oo][jj * 4];
        const float4 wb = *(const float4*)&w_ss[oo + 16][jj * 4];
        const float4 va = *(const float4*)&vn_s[nn][jj * 4];
        const float4 vb = *(const float4*)&vn_s[nn + 16][jj * 4];
        a00 = fmaf(wa.x, va.x, fmaf(wa.y, va.y, fmaf(wa.z, va.z, fmaf(wa.w, va.w, a00))));
        a01 = fmaf(wa.x, vb.x, fmaf(wa.y, vb.y, fmaf(wa.z, vb.z, fmaf(wa.w, vb.w, a01))));
        a10 = fmaf(wb.x, va.x, fmaf(wb.y, va.y, fmaf(wb.z, va.z, fmaf(wb.w, va.w, a10))));
        a11 = fmaf(wb.x, vb.x, fmaf(wb.y, vb.y, fmaf(wb.z, vb.z, fmaf(wb.w, vb.w, a11))));
    }
    const int ob = og * 32;
    part2[(jc * 32 + nn)      * 256 + ob + oo]      = a00;
    part2[(jc * 32 + nn + 16) * 256 + ob + oo]      = a01;
    part2[(jc * 32 + nn)      * 256 + ob + oo + 16] = a10;
    part2[(jc * 32 + nn + 16) * 256 + ob + oo + 16] = a11;
}

// ---------------------------------------------------------------------------
// Kernel D: reduce j-slices, global-norm scale, bias, final L2 norm.
// ---------------------------------------------------------------------------
__global__ __launch_bounds__(256)
void k_finalize(const float* __restrict__ part2, const float* __restrict__ mlp_b,
                const float* __restrict__ rsq, float* __restrict__ out)
{
    const int n = blockIdx.x, o = threadIdx.x;
    float g = 0.f;
#pragma unroll
    for (int i = 0; i < 16; ++i) {
        const float4 r = *(const float4*)&rsq[n * K_CL + i * 4];
        g += r.x + r.y + r.z + r.w;
    }
    const float s = 1.0f / fmaxf(sqrtf(g), 1e-12f);
    float acc = 0.f;
#pragma unroll
    for (int jc = 0; jc < 32; ++jc) acc += part2[(jc * 32 + n) * 256 + o];
    const float y = fmaf(acc, s, mlp_b[o]);
    float sq = y * y;
#pragma unroll
    for (int m = 1; m < 64; m <<= 1) sq += __shfl_xor(sq, m);
    __shared__ float red[4];
    if ((o & 63) == 0) red[o >> 6] = sq;
    __syncthreads();
    const float tot = red[0] + red[1] + red[2] + red[3];
    out[n * OUT_D + o] = y / fmaxf(sqrtf(tot), 1e-12f);
}

// ---------------------------------------------------------------------------
extern "C" void kernel_launch(void* const* d_in, const int* in_sizes, int n_in,
                              void* d_out, int out_size, void* d_ws, size_t ws_size,
                              hipStream_t stream)
{
    const float* x       = (const float*)d_in[0];
    const float* centers = (const float*)d_in[1];
    const float* conv_w  = (const float*)d_in[2];
    const float* conv_b  = (const float*)d_in[3];
    const float* mlp_w   = (const float*)d_in[4];
    const float* mlp_b   = (const float*)d_in[5];

    float* ws    = (float*)d_ws;
    float* part  = ws;                         // 512*8448 = 4,325,376 f
    float* vnorm = part + 512 * PART_BLK;      // 262,144 f
    float* rsq   = vnorm + 32 * 8192;          // 2,048 f
    float* part2 = rsq + 2048;                 // 262,144 f

    k_vlad_mfma<<<dim3(512), dim3(256), 0, stream>>>(x, conv_w, conv_b, part);
    k_reduce_norm<<<dim3(2048), dim3(128), 0, stream>>>(part, centers, vnorm, rsq);
    k_mlp<<<dim3(256), dim3(256), 0, stream>>>(vnorm, mlp_w, part2);
    k_finalize<<<dim3(32), dim3(256), 0, stream>>>(part2, mlp_b, rsq, (float*)d_out);
}

// Round 3
// 45.689 us; speedup vs baseline: 2.1531x; 1.1431x over previous
//
#include <hip/hip_runtime.h>
#include <math.h>

// NetVLAD fused pipeline, MFMA bf16.
// x[32][128][4096], conv_w[64][128], conv_b[64], centers[64][128],
// mlp_w[256][8192], mlp_b[256], out[32][256].

#define N_IMG 32
#define C_DIM 128
#define P_PIX 4096
#define K_CL  64
#define OUT_D 256

#define CHUNKS 8               // chunks per image (512 px each)
#define NSUB 4                 // 128-px subchunks per chunk
#define PART_ROW 132
#define PART_BLK (K_CL * PART_ROW)

typedef __attribute__((ext_vector_type(8))) short bf16x8;
typedef __attribute__((ext_vector_type(4))) short bf16x4;
typedef __attribute__((ext_vector_type(4))) float f32x4;
typedef __attribute__((ext_vector_type(2))) unsigned u32x2;
typedef __attribute__((ext_vector_type(4))) unsigned u32x4;

// pack two fp32 -> bf16 pair (RTNE), low = a, high = b
__device__ __forceinline__ unsigned bfpk(float a, float b) {
    union { float f; unsigned u; } x, y;
    x.f = a; y.f = b;
    unsigned lo = (x.u + 0x7FFFu + ((x.u >> 16) & 1u)) >> 16;
    unsigned hi = (y.u + 0x7FFFu + ((y.u >> 16) & 1u)) & 0xFFFF0000u;
    return lo | hi;
}
__device__ __forceinline__ unsigned short bf1(float a) {
    union { float f; unsigned u; } x; x.f = a;
    return (unsigned short)((x.u + 0x7FFFu + ((x.u >> 16) & 1u)) >> 16);
}

__device__ __forceinline__ f32x4 mfma16(bf16x8 a, bf16x8 b, f32x4 c) {
    return __builtin_amdgcn_mfma_f32_16x16x32_bf16(a, b, c, 0, 0, 0);
}

// hardware transpose read: 4 bf16 at addr + {0,32,64,96} bytes
__device__ __forceinline__ u32x2 tr16(unsigned addr) {
    u32x2 d;
    asm volatile("ds_read_b64_tr_b16 %0, %1" : "=v"(d) : "v"(addr));
    return d;
}
__device__ __forceinline__ u32x2 tr16_o1024(unsigned addr) {
    u32x2 d;
    asm volatile("ds_read_b64_tr_b16 %0, %1 offset:1024" : "=v"(d) : "v"(addr));
    return d;
}

// raw barrier: drain LDS only, leave global prefetch loads in flight
// (avoids __syncthreads' s_waitcnt vmcnt(0) drain)
__device__ __forceinline__ void bar_lgkm() {
    __builtin_amdgcn_sched_barrier(0);
    asm volatile("s_waitcnt lgkmcnt(0)" ::: "memory");
    __builtin_amdgcn_s_barrier();
    __builtin_amdgcn_sched_barrier(0);
}

// ---------------------------------------------------------------------------
// Kernel A: fused conv-logits + softmax + VLAD partials on MFMA.
// grid = 256 (n = bid>>3, 512-px chunk = bid&7), block = 256 (4 waves).
// 4 subchunks of 128 px, software-pipelined global loads that survive the
// (raw) barriers. LDS ~49 KB.
// ---------------------------------------------------------------------------
__global__ __launch_bounds__(256)
void k_vlad_mfma(const float* __restrict__ x, const float* __restrict__ conv_w,
                 const float* __restrict__ conv_b, float* __restrict__ part)
{
    __shared__ short xc_s[16384];   // x subtiled [c>>2][p>>4][c&3][p&15], 32 KB
    __shared__ short a_s[8192];     // a[k][p] bf16, byte ^ ((k&7)<<4), 16 KB
    __shared__ float asred[256];

    const int t   = threadIdx.x;
    const int w   = t >> 6;
    const int l   = t & 63;
    const int l15 = l & 15;
    const int lg  = l >> 4;
    const int n   = blockIdx.x >> 3;
    const int ch  = blockIdx.x & 7;
    const int pb0 = ch * 512;

    const unsigned xc_base = (unsigned)(unsigned long long)(void*)xc_s;

    // ---- prologue: issue subchunk-0 x loads first ----
    const float* xr0 = x + ((long)n * C_DIM + 32 * w + l15) * P_PIX;
    const float* xr1 = xr0 + 16 * P_PIX;
    float4 raw[16];
#pragma unroll
    for (int h = 0; h < 2; ++h) {
        const float* xr = h ? xr1 : xr0;
#pragma unroll
        for (int ks = 0; ks < 4; ++ks) {
            const float* p = xr + pb0 + ks * 32 + lg * 8;
            raw[(h * 4 + ks) * 2 + 0] = *(const float4*)(p);
            raw[(h * 4 + ks) * 2 + 1] = *(const float4*)(p + 4);
        }
    }

    // ---- W fragments (GEMM1 B-operand) ----
    bf16x8 wf[4][4];
#pragma unroll
    for (int nt = 0; nt < 4; ++nt) {
        const float* wr = conv_w + (nt * 16 + l15) * C_DIM;
#pragma unroll
        for (int ks = 0; ks < 4; ++ks) {
            float4 a = *(const float4*)(wr + ks * 32 + lg * 8);
            float4 b = *(const float4*)(wr + ks * 32 + lg * 8 + 4);
            union { u32x4 u; bf16x8 v; } cv;
            cv.u.x = bfpk(a.x, a.y); cv.u.y = bfpk(a.z, a.w);
            cv.u.z = bfpk(b.x, b.y); cv.u.w = bfpk(b.z, b.w);
            wf[nt][ks] = cv.v;
        }
    }
    float bias[4];
#pragma unroll
    for (int nt = 0; nt < 4; ++nt) bias[nt] = conv_b[nt * 16 + l15];

    f32x4 acc2[4][2];
#pragma unroll
    for (int mt = 0; mt < 4; ++mt)
#pragma unroll
        for (int h = 0; h < 2; ++h)
            acc2[mt][h] = (f32x4){0.f, 0.f, 0.f, 0.f};
    float asum[4] = {0.f, 0.f, 0.f, 0.f};
    bf16x8 oct[2][4];

#pragma unroll
    for (int s = 0; s < NSUB; ++s) {
        // ---- convert raw -> bf16 octets (waits this subchunk's loads) ----
#pragma unroll
        for (int h = 0; h < 2; ++h)
#pragma unroll
            for (int ks = 0; ks < 4; ++ks) {
                const float4 A = raw[(h * 4 + ks) * 2];
                const float4 B = raw[(h * 4 + ks) * 2 + 1];
                union { u32x4 u; bf16x8 v; } cv;
                cv.u.x = bfpk(A.x, A.y); cv.u.y = bfpk(A.z, A.w);
                cv.u.z = bfpk(B.x, B.y); cv.u.w = bfpk(B.z, B.w);
                oct[h][ks] = cv.v;
            }
        // ---- stage into subtiled xc ----
#pragma unroll
        for (int h = 0; h < 2; ++h)
#pragma unroll
            for (int ks = 0; ks < 4; ++ks) {
                const int c  = 32 * w + 16 * h + l15;
                const int pl = ks * 32 + lg * 8;
                const unsigned off = (unsigned)((c >> 2) * 1024 + (pl >> 4) * 128
                                                + (c & 3) * 32 + (pl & 15) * 2);
                *(bf16x8*)((char*)xc_s + off) = oct[h][ks];
            }
        // ---- prefetch next subchunk (stays in flight across barriers) ----
        if (s + 1 < NSUB) {
#pragma unroll
            for (int h = 0; h < 2; ++h) {
                const float* xr = h ? xr1 : xr0;
#pragma unroll
                for (int ks = 0; ks < 4; ++ks) {
                    const float* p = xr + pb0 + (s + 1) * 128 + ks * 32 + lg * 8;
                    raw[(h * 4 + ks) * 2 + 0] = *(const float4*)(p);
                    raw[(h * 4 + ks) * 2 + 1] = *(const float4*)(p + 4);
                }
            }
        }
        bar_lgkm();   // B1: xc staged (GEMM2 of prev subchunk done by all)

        // ---- GEMM1: logits^T[p][k] ----
        f32x4 acc1[2][4];
#pragma unroll
        for (int pt2 = 0; pt2 < 2; ++pt2)
#pragma unroll
            for (int nt = 0; nt < 4; ++nt)
                acc1[pt2][nt] = (f32x4){0.f, 0.f, 0.f, 0.f};
#pragma unroll
        for (int ks = 0; ks < 4; ++ks) {
            const unsigned ab = xc_base
                + (unsigned)((ks * 8 + lg * 2) * 1024 + l15 * 2);
            u32x2 t00 = tr16(ab + (2 * w + 0) * 128);
            u32x2 t01 = tr16_o1024(ab + (2 * w + 0) * 128);
            u32x2 t10 = tr16(ab + (2 * w + 1) * 128);
            u32x2 t11 = tr16_o1024(ab + (2 * w + 1) * 128);
            asm volatile("s_waitcnt lgkmcnt(0)" ::: "memory");
            __builtin_amdgcn_sched_barrier(0);
            union { u32x4 u; bf16x8 v; } a0, a1;
            a0.u = (u32x4){t00.x, t00.y, t01.x, t01.y};
            a1.u = (u32x4){t10.x, t10.y, t11.x, t11.y};
#pragma unroll
            for (int nt = 0; nt < 4; ++nt) {
                acc1[0][nt] = mfma16(a0.v, wf[nt][ks], acc1[0][nt]);
                acc1[1][nt] = mfma16(a1.v, wf[nt][ks], acc1[1][nt]);
            }
        }

        // ---- softmax over k (in-register, 16-lane groups) ----
#pragma unroll
        for (int pt2 = 0; pt2 < 2; ++pt2) {
#pragma unroll
            for (int r = 0; r < 4; ++r) {
                float v0 = acc1[pt2][0][r] + bias[0];
                float v1 = acc1[pt2][1][r] + bias[1];
                float v2 = acc1[pt2][2][r] + bias[2];
                float v3 = acc1[pt2][3][r] + bias[3];
                float m = fmaxf(fmaxf(v0, v1), fmaxf(v2, v3));
                m = fmaxf(m, __shfl_xor(m, 1));
                m = fmaxf(m, __shfl_xor(m, 2));
                m = fmaxf(m, __shfl_xor(m, 4));
                m = fmaxf(m, __shfl_xor(m, 8));
                v0 = __expf(v0 - m); v1 = __expf(v1 - m);
                v2 = __expf(v2 - m); v3 = __expf(v3 - m);
                float sm = v0 + v1 + v2 + v3;
                sm += __shfl_xor(sm, 1);
                sm += __shfl_xor(sm, 2);
                sm += __shfl_xor(sm, 4);
                sm += __shfl_xor(sm, 8);
                const float inv = __fdividef(1.0f, sm);
                v0 *= inv; v1 *= inv; v2 *= inv; v3 *= inv;
                asum[0] += v0; asum[1] += v1; asum[2] += v2; asum[3] += v3;
                acc1[pt2][0][r] = v0; acc1[pt2][1][r] = v1;
                acc1[pt2][2][r] = v2; acc1[pt2][3][r] = v3;
            }
        }
        // ---- write a -> a_s (swizzled) ----
#pragma unroll
        for (int pt2 = 0; pt2 < 2; ++pt2) {
            const int pbyte = (2 * w + pt2) * 32 + lg * 8;
#pragma unroll
            for (int nt = 0; nt < 4; ++nt) {
                const int k = nt * 16 + l15;
                union { u32x2 u; bf16x4 v; } pk4;
                pk4.u.x = bfpk(acc1[pt2][nt][0], acc1[pt2][nt][1]);
                pk4.u.y = bfpk(acc1[pt2][nt][2], acc1[pt2][nt][3]);
                const unsigned off =
                    (unsigned)(k * 256 + (pbyte ^ ((k & 7) << 4)));
                *(bf16x4*)((char*)a_s + off) = pk4.v;
            }
        }
        bar_lgkm();   // B2: a ready

        // ---- GEMM2: vlad[k][c] += a[k][p] @ x^T[p][c] ----
#pragma unroll
        for (int ks = 0; ks < 4; ++ks) {
            bf16x8 af[4];
#pragma unroll
            for (int mt = 0; mt < 4; ++mt) {
                const int k = mt * 16 + l15;
                const unsigned off = (unsigned)(k * 256
                    + ((ks * 64 + lg * 16) ^ ((k & 7) << 4)));
                af[mt] = *(const bf16x8*)((char*)a_s + off);
            }
#pragma unroll
            for (int mt = 0; mt < 4; ++mt)
#pragma unroll
                for (int h = 0; h < 2; ++h)
                    acc2[mt][h] = mfma16(af[mt], oct[h][ks], acc2[mt][h]);
        }
    }

    // ---- write partials: part[bid][k][c], asum at c=128 ----
    const long pbase = (long)blockIdx.x * PART_BLK;
#pragma unroll
    for (int mt = 0; mt < 4; ++mt)
#pragma unroll
        for (int h = 0; h < 2; ++h) {
            const int c = 32 * w + 16 * h + l15;
#pragma unroll
            for (int r = 0; r < 4; ++r) {
                const int k = mt * 16 + lg * 4 + r;
                part[pbase + (long)k * PART_ROW + c] = acc2[mt][h][r];
            }
        }
#pragma unroll
    for (int nt = 0; nt < 4; ++nt) {
        float a = asum[nt];
        a += __shfl_xor(a, 16);
        a += __shfl_xor(a, 32);
        if (lg == 0) asred[w * 64 + nt * 16 + l15] = a;
    }
    __syncthreads();
    if (t < 64) {
        float a = asred[t] + asred[64 + t] + asred[128 + t] + asred[192 + t];
        part[pbase + (long)t * PART_ROW + 128] = a;
    }
}

// ---------------------------------------------------------------------------
// Kernel B: reduce partials, subtract asum*centers, intra-normalize.
// Emits bf16 vnorm (for MFMA MLP) + per-row rsq.
// grid = 2048 (n = b>>6, k = b&63), block = 128 (c = tid).
// ---------------------------------------------------------------------------
__global__ __launch_bounds__(128)
void k_reduce_norm(const float* __restrict__ part, const float* __restrict__ centers,
                   unsigned short* __restrict__ vn16, float* __restrict__ rsq)
{
    const int b = blockIdx.x;
    const int n = b >> 6, k = b & 63;
    const int c = threadIdx.x;
    float acc = 0.f, as = 0.f;
#pragma unroll
    for (int ch = 0; ch < CHUNKS; ++ch) {
        const float* p = part + ((long)(n * CHUNKS + ch) * PART_BLK + k * PART_ROW);
        acc += p[c];
        as  += p[128];
    }
    const float v = fmaf(-as, centers[k * C_DIM + c], acc);
    float sq = v * v;
#pragma unroll
    for (int m = 1; m < 64; m <<= 1) sq += __shfl_xor(sq, m);
    __shared__ float red[2];
    if ((c & 63) == 0) red[c >> 6] = sq;
    __syncthreads();
    const float total = red[0] + red[1];
    const float s = 1.0f / fmaxf(sqrtf(total), 1e-12f);
    vn16[(long)n * 8192 + k * C_DIM + c] = bf1(v * s);
    if (c == 0) rsq[n * K_CL + k] = total * s * s;
}

// ---------------------------------------------------------------------------
// Kernel C: MLP GEMM on MFMA bf16, no LDS. grid = 256 (jc = b>>3, og = b&7),
// block = 64 (1 wave). Each block: [32n x 32o] over a 256-wide j slice.
// mlp_w read exactly once chip-wide; vnorm bf16 re-read 8x (4 MB).
// ---------------------------------------------------------------------------
__global__ __launch_bounds__(64, 1)
void k_mlp_mfma(const unsigned short* __restrict__ vn16,
                const float* __restrict__ mlp_w, float* __restrict__ part2)
{
    const int t = threadIdx.x;
    const int l15 = t & 15, lg = t >> 4;
    const int jc = blockIdx.x >> 3, og = blockIdx.x & 7;
    const int j0 = jc * 256;

    // A-frags: vnorm rows (n = mt*16 + l15), 8 j-elems each
    bf16x8 af[2][8];
#pragma unroll
    for (int mt = 0; mt < 2; ++mt)
#pragma unroll
        for (int kk = 0; kk < 8; ++kk)
            af[mt][kk] = *(const bf16x8*)&vn16[(long)(mt * 16 + l15) * 8192
                                              + j0 + kk * 32 + lg * 8];
    // B-frags: w rows (o = og*32 + ot*16 + l15), fp32 -> bf16
    bf16x8 bfr[2][8];
#pragma unroll
    for (int ot = 0; ot < 2; ++ot) {
        const float* wp = mlp_w + (long)(og * 32 + ot * 16 + l15) * 8192 + j0;
#pragma unroll
        for (int kk = 0; kk < 8; ++kk) {
            float4 a = *(const float4*)(wp + kk * 32 + lg * 8);
            float4 b = *(const float4*)(wp + kk * 32 + lg * 8 + 4);
            union { u32x4 u; bf16x8 v; } cv;
            cv.u.x = bfpk(a.x, a.y); cv.u.y = bfpk(a.z, a.w);
            cv.u.z = bfpk(b.x, b.y); cv.u.w = bfpk(b.z, b.w);
            bfr[ot][kk] = cv.v;
        }
    }

    f32x4 acc[2][2];
#pragma unroll
    for (int mt = 0; mt < 2; ++mt)
#pragma unroll
        for (int ot = 0; ot < 2; ++ot)
            acc[mt][ot] = (f32x4){0.f, 0.f, 0.f, 0.f};
#pragma unroll
    for (int kk = 0; kk < 8; ++kk)
#pragma unroll
        for (int mt = 0; mt < 2; ++mt)
#pragma unroll
            for (int ot = 0; ot < 2; ++ot)
                acc[mt][ot] = mfma16(af[mt][kk], bfr[ot][kk], acc[mt][ot]);

    // part2 layout [n][jc][o] for coalesced finalize reads
#pragma unroll
    for (int mt = 0; mt < 2; ++mt)
#pragma unroll
        for (int ot = 0; ot < 2; ++ot)
#pragma unroll
            for (int r = 0; r < 4; ++r) {
                const int nn = mt * 16 + lg * 4 + r;
                const int oo = og * 32 + ot * 16 + l15;
                part2[(long)nn * 8192 + jc * 256 + oo] = acc[mt][ot][r];
            }
}

// ---------------------------------------------------------------------------
// Kernel D: reduce j-slices, global-norm scale, bias, final L2 norm.
// grid = 32 (n), block = 256 (o).
// ---------------------------------------------------------------------------
__global__ __launch_bounds__(256)
void k_finalize(const float* __restrict__ part2, const float* __restrict__ mlp_b,
                const float* __restrict__ rsq, float* __restrict__ out)
{
    const int n = blockIdx.x, o = threadIdx.x;
    float g = 0.f;
#pragma unroll
    for (int i = 0; i < 16; ++i) {
        const float4 r = *(const float4*)&rsq[n * K_CL + i * 4];
        g += r.x + r.y + r.z + r.w;
    }
    const float s = 1.0f / fmaxf(sqrtf(g), 1e-12f);
    float acc = 0.f;
#pragma unroll
    for (int jc = 0; jc < 32; ++jc) acc += part2[(long)n * 8192 + jc * 256 + o];
    const float y = fmaf(acc, s, mlp_b[o]);
    float sq = y * y;
#pragma unroll
    for (int m = 1; m < 64; m <<= 1) sq += __shfl_xor(sq, m);
    __shared__ float red[4];
    if ((o & 63) == 0) red[o >> 6] = sq;
    __syncthreads();
    const float tot = red[0] + red[1] + red[2] + red[3];
    out[n * OUT_D + o] = y / fmaxf(sqrtf(tot), 1e-12f);
}

// ---------------------------------------------------------------------------
extern "C" void kernel_launch(void* const* d_in, const int* in_sizes, int n_in,
                              void* d_out, int out_size, void* d_ws, size_t ws_size,
                              hipStream_t stream)
{
    const float* x       = (const float*)d_in[0];
    const float* centers = (const float*)d_in[1];
    const float* conv_w  = (const float*)d_in[2];
    const float* conv_b  = (const float*)d_in[3];
    const float* mlp_w   = (const float*)d_in[4];
    const float* mlp_b   = (const float*)d_in[5];

    float* ws = (float*)d_ws;
    float* part = ws;                                   // 256*8448 = 2,162,688 f
    unsigned short* vn16 = (unsigned short*)(part + 256 * PART_BLK);  // 262,144 u16
    float* rsq   = (float*)(vn16 + 32 * 8192);          // 2,048 f
    float* part2 = rsq + 2048;                          // 32*8192 f

    k_vlad_mfma<<<dim3(256), dim3(256), 0, stream>>>(x, conv_w, conv_b, part);
    k_reduce_norm<<<dim3(2048), dim3(128), 0, stream>>>(part, centers, vn16, rsq);
    k_mlp_mfma<<<dim3(256), dim3(64), 0, stream>>>(vn16, mlp_w, part2);
    k_finalize<<<dim3(32), dim3(256), 0, stream>>>(part2, mlp_b, rsq, (float*)d_out);
}